// Round 4
// baseline (269.539 us; speedup 1.0000x reference)
//
#include <hip/hip_runtime.h>
#include <cstdint>

// CRF loss forward, B=4096 T=512 L=16 — linear-space recursion, all-VALU matvec v2.
// One batch per wave64. All 4 rows (16-lane groups) hold IDENTICAL alpha[l16].
// Step: acc = sum_{k=0..15} ror_k(av) * m_k  (15 DPP row_ror + 16 FMA, 4 split
// accumulators), av = acc * exp(x_t[l16]).  The index map i_k = ror_k(lane)
// is derived at init through the SAME DPP ops, so the 16 (value, constant)
// pairs match under either rotation direction — complete partition trivially.
// No permlane, no cross-row ops. Renorm by alpha[0] (readfirstlane+rcp) every
// 4 steps and at chunk end. x staged via global_load_lds (64-step chunks,
// double-buffered, vmcnt(5)); em/ts scores per-chunk parallel (lane = t) —
// verbatim from the verified R2 kernel.

static constexpr float L2E = 1.4426950408889634f;   // log2(e)
static constexpr float LN2 = 0.69314718055994531f;  // ln(2)

__device__ __forceinline__ void gload_lds16(const void* g, void* l) {
  __builtin_amdgcn_global_load_lds((const __attribute__((address_space(1))) unsigned int*)g,
                                   (__attribute__((address_space(3))) unsigned int*)l, 16, 0, 0);
}
__device__ __forceinline__ void gload_lds4(const void* g, void* l) {
  __builtin_amdgcn_global_load_lds((const __attribute__((address_space(1))) unsigned int*)g,
                                   (__attribute__((address_space(3))) unsigned int*)l, 4, 0, 0);
}
__device__ __forceinline__ void wait_vm0() { asm volatile("s_waitcnt vmcnt(0)" ::: "memory"); }
__device__ __forceinline__ void wait_vm5() { asm volatile("s_waitcnt vmcnt(5)" ::: "memory"); }

// DPP row_ror:N (ctrl = 0x120 | N), all lanes, within each 16-lane row
template <int CTRL>
__device__ __forceinline__ float dppf(float v) {
  return __builtin_bit_cast(float,
      __builtin_amdgcn_mov_dpp(__builtin_bit_cast(int, v), CTRL, 0xF, 0xF, true));
}
template <int CTRL>
__device__ __forceinline__ int dppi(int v) {
  return __builtin_amdgcn_mov_dpp(v, CTRL, 0xF, 0xF, true);
}
__device__ __forceinline__ float rfl(float v) {
  return __builtin_bit_cast(float, __builtin_amdgcn_readfirstlane(__builtin_bit_cast(int, v)));
}

__global__ __launch_bounds__(256, 4) void crf_fwd(
    const float* __restrict__ x, const float* __restrict__ trans,
    const int* __restrict__ label, const int* __restrict__ length,
    float* __restrict__ out) {
  __shared__ float ldsx[4][2][64 * 16];  // per-wave, double-buffered, 64 timesteps x 16 labels
  __shared__ int   ldsl[4][2][64];       // labels per chunk
  __shared__ float ldst[256];            // raw trans table (natural log units)

  const int tid  = threadIdx.x;
  const int wv   = tid >> 6;
  const int lane = tid & 63;
  const int l16  = lane & 15;

  ldst[tid] = trans[tid];  // blockDim == 256 == L*L
  __syncthreads();

  const int b   = blockIdx.x * 4 + wv;
  const int len = length[b];
  const int nch = ((len - 1) >> 6) + 1;  // chunks of 64 timesteps needed

  // --- index map i_k = ror_k(l16), derived through the SAME DPP ops as the steps ---
  const int i1  = dppi<0x121>(l16);
  const int i2  = dppi<0x122>(l16);
  const int i3  = dppi<0x123>(l16);
  const int i4  = dppi<0x124>(l16);
  const int i5  = dppi<0x125>(l16);
  const int i6  = dppi<0x126>(l16);
  const int i7  = dppi<0x127>(l16);
  const int i8  = dppi<0x128>(l16);
  const int i9  = dppi<0x129>(l16);
  const int i10 = dppi<0x12A>(l16);
  const int i11 = dppi<0x12B>(l16);
  const int i12 = dppi<0x12C>(l16);
  const int i13 = dppi<0x12D>(l16);
  const int i14 = dppi<0x12E>(l16);
  const int i15 = dppi<0x12F>(l16);
  // m_k = exp(trans[i_k][l16])
  const float m0  = __builtin_amdgcn_exp2f(trans[l16 * 16 + l16] * L2E);
  const float m1  = __builtin_amdgcn_exp2f(trans[i1  * 16 + l16] * L2E);
  const float m2  = __builtin_amdgcn_exp2f(trans[i2  * 16 + l16] * L2E);
  const float m3  = __builtin_amdgcn_exp2f(trans[i3  * 16 + l16] * L2E);
  const float m4  = __builtin_amdgcn_exp2f(trans[i4  * 16 + l16] * L2E);
  const float m5  = __builtin_amdgcn_exp2f(trans[i5  * 16 + l16] * L2E);
  const float m6  = __builtin_amdgcn_exp2f(trans[i6  * 16 + l16] * L2E);
  const float m7  = __builtin_amdgcn_exp2f(trans[i7  * 16 + l16] * L2E);
  const float m8  = __builtin_amdgcn_exp2f(trans[i8  * 16 + l16] * L2E);
  const float m9  = __builtin_amdgcn_exp2f(trans[i9  * 16 + l16] * L2E);
  const float m10 = __builtin_amdgcn_exp2f(trans[i10 * 16 + l16] * L2E);
  const float m11 = __builtin_amdgcn_exp2f(trans[i11 * 16 + l16] * L2E);
  const float m12 = __builtin_amdgcn_exp2f(trans[i12 * 16 + l16] * L2E);
  const float m13 = __builtin_amdgcn_exp2f(trans[i13 * 16 + l16] * L2E);
  const float m14 = __builtin_amdgcn_exp2f(trans[i14 * 16 + l16] * L2E);
  const float m15 = __builtin_amdgcn_exp2f(trans[i15 * 16 + l16] * L2E);

  const char* xb = (const char*)x + (size_t)b * 32768;      // 512*16*4
  const char* lb = (const char*)label + (size_t)b * 2048;   // 512*4

  auto stage = [&](int c, int buf) {
    const char* gx = xb + c * 4096;
    float* lxp = &ldsx[wv][buf][0];
    gload_lds16(gx + 0 * 1024 + lane * 16, lxp + 0 * 256);
    gload_lds16(gx + 1 * 1024 + lane * 16, lxp + 1 * 256);
    gload_lds16(gx + 2 * 1024 + lane * 16, lxp + 2 * 256);
    gload_lds16(gx + 3 * 1024 + lane * 16, lxp + 3 * 256);
    gload_lds4(lb + c * 256 + lane * 4, &ldsl[wv][buf][0]);
  };

  stage(0, 0);

  float av = 1.0f;  // alpha[l16] / 2^R2 (identical across the 4 rows)
  float R2 = 0.0f;  // accumulated base-2 renormalization (wave-uniform)
  float em = 0.0f;  // emission score (per-lane partial, natural units)
  float ts = 0.0f;  // transition score (per-lane partial, natural units)
  int lastl = 0;    // label at last timestep of previous chunk

  auto step = [&](float xe) {
    float a0 = av * m0;
    float a1 = dppf<0x124>(av) * m4;
    float a2 = dppf<0x128>(av) * m8;
    float a3 = dppf<0x12C>(av) * m12;
    a0 = __builtin_fmaf(dppf<0x121>(av), m1,  a0);
    a1 = __builtin_fmaf(dppf<0x125>(av), m5,  a1);
    a2 = __builtin_fmaf(dppf<0x129>(av), m9,  a2);
    a3 = __builtin_fmaf(dppf<0x12D>(av), m13, a3);
    a0 = __builtin_fmaf(dppf<0x122>(av), m2,  a0);
    a1 = __builtin_fmaf(dppf<0x126>(av), m6,  a1);
    a2 = __builtin_fmaf(dppf<0x12A>(av), m10, a2);
    a3 = __builtin_fmaf(dppf<0x12E>(av), m14, a3);
    a0 = __builtin_fmaf(dppf<0x123>(av), m3,  a0);
    a1 = __builtin_fmaf(dppf<0x127>(av), m7,  a1);
    a2 = __builtin_fmaf(dppf<0x12B>(av), m11, a2);
    a3 = __builtin_fmaf(dppf<0x12F>(av), m15, a3);
    av = ((a0 + a1) + (a2 + a3)) * xe;
  };
  auto renorm = [&]() {
    const float C = rfl(av);  // lane 0 -> alpha[0] > 0
    av *= __builtin_amdgcn_rcpf(C);
    R2 += __builtin_amdgcn_logf(C);  // log2
  };

  for (int c = 0; c < nch; ++c) {
    const int buf = c & 1;
    const bool pre = (c + 1 < nch);
    if (pre) stage(c + 1, buf ^ 1);
    if (pre) wait_vm5(); else wait_vm0();  // chunk c's 5 loads complete (in-order vmcnt)

    float* lx = &ldsx[wv][buf][0];
    int*   ll = &ldsl[wv][buf][0];

    // ---- parallel em/ts pass: lane handles timestep c*64+lane (raw x values) ----
    {
      const int gt   = c * 64 + lane;
      const int lblt = ll[lane];
      const int lprv = (lane == 0) ? lastl : ll[lane - 1];
      const float emv = lx[lane * 16 + lblt];
      const float tsv = ldst[lprv * 16 + lblt];
      if (gt < len) em += emv;
      if (gt >= 1 && gt < len) ts += tsv;
      lastl = __shfl(lblt, 63, 64);
    }

    // ---- in-place transform: x -> exp(x); lane owns floats [lane*16, lane*16+16) ----
    {
      float4* p = (float4*)(lx + lane * 16);
#pragma unroll
      for (int k = 0; k < 4; ++k) {
        float4 v = p[k];
        v.x = __builtin_amdgcn_exp2f(v.x * L2E);
        v.y = __builtin_amdgcn_exp2f(v.y * L2E);
        v.z = __builtin_amdgcn_exp2f(v.z * L2E);
        v.w = __builtin_amdgcn_exp2f(v.w * L2E);
        p[k] = v;
      }
    }

    if (c == 0) av = lx[l16];  // alpha_0 = exp(x[0][:])

    const int start = (c == 0) ? 1 : c * 64;
    const int end   = (len - 1 < c * 64 + 63) ? (len - 1) : (c * 64 + 63);
    int n = end - start + 1;
    if (n > 0) {
      const float* xp = lx + (start & 63) * 16 + l16;
      while (n >= 4) {
        step(xp[0]);
        step(xp[16]);
        step(xp[32]);
        step(xp[48]);
        xp += 64;
        n -= 4;
        renorm();
      }
      if (n > 0) {
        for (int e = 0; e < n; ++e) step(xp[e * 16]);
        renorm();
      }
    }
  }

  // stot = sum_j alpha[j] via in-row rotate-and-add (direction-independent)
  float stot = av;
  stot += dppf<0x128>(stot);  // ror 8
  stot += dppf<0x124>(stot);  // ror 4
  stot += dppf<0x122>(stot);  // ror 2
  stot += dppf<0x121>(stot);  // ror 1

  em += __shfl_xor(em, 1, 64);
  em += __shfl_xor(em, 2, 64);
  em += __shfl_xor(em, 4, 64);
  em += __shfl_xor(em, 8, 64);
  em += __shfl_xor(em, 16, 64);
  em += __shfl_xor(em, 32, 64);

  ts += __shfl_xor(ts, 1, 64);
  ts += __shfl_xor(ts, 2, 64);
  ts += __shfl_xor(ts, 4, 64);
  ts += __shfl_xor(ts, 8, 64);
  ts += __shfl_xor(ts, 16, 64);
  ts += __shfl_xor(ts, 32, 64);

  const float z2 = R2 + __builtin_amdgcn_logf(stot);
  const float res = z2 * LN2 - em - ts;
  if (lane == 0) out[b] = res;
}

extern "C" void kernel_launch(void* const* d_in, const int* in_sizes, int n_in,
                              void* d_out, int out_size, void* d_ws, size_t ws_size,
                              hipStream_t stream) {
  const float* x      = (const float*)d_in[0];
  const float* trans  = (const float*)d_in[1];
  const int*   label  = (const int*)d_in[2];
  const int*   length = (const int*)d_in[3];
  float* out = (float*)d_out;
  const int B = in_sizes[3];  // 4096
  crf_fwd<<<dim3(B / 4), dim3(256), 0, stream>>>(x, trans, label, length, out);
}

// Round 5
// 228.861 us; speedup vs baseline: 1.1777x; 1.1777x over previous
//
#include <hip/hip_runtime.h>
#include <cstdint>

// CRF loss forward, B=4096 T=512 L=16 — linear-space, all-VALU matvec,
// 4 batches per wave64 (one per 16-lane row; DPP row_ror never crosses rows).
// Step (serves 4 batches): acc = sum_k ror_k(av)*m_k (15 DPP + 16 mul/fma),
// av = (t < mylen) ? acc*exp(x_t) : av.  Index map i_k = ror_k(lane) derived
// at init through the SAME DPP ops (direction-proof, verified in R4).
// Renorm every 8 steps: C = row-sum via 4 DPP rotate-adds (direction-proof),
// scale by exact power-of-2 from C's exponent bits (no rcp/log, no LDS).
// x staged via global_load_lds, 64-step chunks, double-buffered, vmcnt(20).
// em/ts per-chunk parallel: lane l16 covers 4 timesteps of its row's batch.

static constexpr float L2E = 1.4426950408889634f;   // log2(e)
static constexpr float LN2 = 0.69314718055994531f;  // ln(2)

__device__ __forceinline__ void gload_lds16(const void* g, void* l) {
  __builtin_amdgcn_global_load_lds((const __attribute__((address_space(1))) unsigned int*)g,
                                   (__attribute__((address_space(3))) unsigned int*)l, 16, 0, 0);
}
__device__ __forceinline__ void gload_lds4(const void* g, void* l) {
  __builtin_amdgcn_global_load_lds((const __attribute__((address_space(1))) unsigned int*)g,
                                   (__attribute__((address_space(3))) unsigned int*)l, 4, 0, 0);
}

// DPP row_ror:N (ctrl = 0x120 | N), within each 16-lane row
template <int CTRL>
__device__ __forceinline__ float dppf(float v) {
  return __builtin_bit_cast(float,
      __builtin_amdgcn_mov_dpp(__builtin_bit_cast(int, v), CTRL, 0xF, 0xF, true));
}
template <int CTRL>
__device__ __forceinline__ int dppi(int v) {
  return __builtin_amdgcn_mov_dpp(v, CTRL, 0xF, 0xF, true);
}

__global__ __launch_bounds__(256, 1) void crf_fwd(
    const float* __restrict__ x, const float* __restrict__ trans,
    const int* __restrict__ label, const int* __restrict__ length,
    float* __restrict__ out) {
  __shared__ float ldsx[4][2][4 * 1032];  // per wave, per buf: 4 regions (1024 x + 8 pad)
  __shared__ int   ldsl[4][2][4][64];     // labels per chunk per batch
  __shared__ float ldst[256];             // raw trans table

  const int tid  = threadIdx.x;
  const int wv   = tid >> 6;
  const int lane = tid & 63;
  const int l16  = lane & 15;
  const int row  = lane >> 4;

  ldst[tid] = trans[tid];
  __syncthreads();

  const int wb0   = blockIdx.x * 16 + wv * 4;  // wave's first batch
  const int myb   = wb0 + row;                 // this row's batch (row-uniform)
  const int mylen = length[myb];
  int mx = mylen;
  { int o = __shfl_xor(mx, 16, 64); mx = mx > o ? mx : o; }
  { int o = __shfl_xor(mx, 32, 64); mx = mx > o ? mx : o; }
  const int maxlen = __builtin_amdgcn_readfirstlane(mx);
  const int nch = ((maxlen - 1) >> 6) + 1;

  // --- index map i_k = ror_k(l16) through the SAME DPP ops as the steps ---
  const int i1  = dppi<0x121>(l16);
  const int i2  = dppi<0x122>(l16);
  const int i3  = dppi<0x123>(l16);
  const int i4  = dppi<0x124>(l16);
  const int i5  = dppi<0x125>(l16);
  const int i6  = dppi<0x126>(l16);
  const int i7  = dppi<0x127>(l16);
  const int i8  = dppi<0x128>(l16);
  const int i9  = dppi<0x129>(l16);
  const int i10 = dppi<0x12A>(l16);
  const int i11 = dppi<0x12B>(l16);
  const int i12 = dppi<0x12C>(l16);
  const int i13 = dppi<0x12D>(l16);
  const int i14 = dppi<0x12E>(l16);
  const int i15 = dppi<0x12F>(l16);
  const float m0  = __builtin_amdgcn_exp2f(trans[l16 * 16 + l16] * L2E);
  const float m1  = __builtin_amdgcn_exp2f(trans[i1  * 16 + l16] * L2E);
  const float m2  = __builtin_amdgcn_exp2f(trans[i2  * 16 + l16] * L2E);
  const float m3  = __builtin_amdgcn_exp2f(trans[i3  * 16 + l16] * L2E);
  const float m4  = __builtin_amdgcn_exp2f(trans[i4  * 16 + l16] * L2E);
  const float m5  = __builtin_amdgcn_exp2f(trans[i5  * 16 + l16] * L2E);
  const float m6  = __builtin_amdgcn_exp2f(trans[i6  * 16 + l16] * L2E);
  const float m7  = __builtin_amdgcn_exp2f(trans[i7  * 16 + l16] * L2E);
  const float m8  = __builtin_amdgcn_exp2f(trans[i8  * 16 + l16] * L2E);
  const float m9  = __builtin_amdgcn_exp2f(trans[i9  * 16 + l16] * L2E);
  const float m10 = __builtin_amdgcn_exp2f(trans[i10 * 16 + l16] * L2E);
  const float m11 = __builtin_amdgcn_exp2f(trans[i11 * 16 + l16] * L2E);
  const float m12 = __builtin_amdgcn_exp2f(trans[i12 * 16 + l16] * L2E);
  const float m13 = __builtin_amdgcn_exp2f(trans[i13 * 16 + l16] * L2E);
  const float m14 = __builtin_amdgcn_exp2f(trans[i14 * 16 + l16] * L2E);
  const float m15 = __builtin_amdgcn_exp2f(trans[i15 * 16 + l16] * L2E);

  auto stage = [&](int c, int buf) {
#pragma unroll
    for (int q = 0; q < 4; ++q) {
      const char* gx = (const char*)x + (size_t)(wb0 + q) * 32768 + (size_t)c * 4096;
      float* dst = &ldsx[wv][buf][q * 1032];
      gload_lds16(gx + 0 * 1024 + lane * 16, dst + 0 * 256);
      gload_lds16(gx + 1 * 1024 + lane * 16, dst + 1 * 256);
      gload_lds16(gx + 2 * 1024 + lane * 16, dst + 2 * 256);
      gload_lds16(gx + 3 * 1024 + lane * 16, dst + 3 * 256);
      gload_lds4((const char*)label + (size_t)(wb0 + q) * 2048 + (size_t)c * 256 + lane * 4,
                 &ldsl[wv][buf][q][0]);
    }
  };

  stage(0, 0);

  float av = 1.0f;  // alpha_{batch row}[l16] / 2^R2
  int   R2 = 0;     // base-2 renorm exponent (row-uniform)
  float em = 0.0f, ts = 0.0f;
  int lastl = 0;    // row's batch label at end of previous chunk
  int t = 1;        // global timestep of next transition

  auto renorm = [&]() {
    float C = av;
    C += dppf<0x128>(C);
    C += dppf<0x124>(C);
    C += dppf<0x122>(C);
    C += dppf<0x121>(C);  // row-sum, row-uniform, > 0
    const int biased = (__builtin_bit_cast(int, C) >> 23) & 0xFF;
    av *= __builtin_bit_cast(float, (254 - biased) << 23);  // exact 2^-(biased-127)
    R2 += biased - 127;
  };

  for (int c = 0; c < nch; ++c) {
    const int buf = c & 1;
    if (c + 1 < nch) {
      stage(c + 1, buf ^ 1);
      asm volatile("s_waitcnt vmcnt(20)" ::: "memory");  // chunk c's 20 loads done
    } else {
      asm volatile("s_waitcnt vmcnt(0)" ::: "memory");
    }

    float* xreg = &ldsx[wv][buf][row * 1032];
    int*   ll   = &ldsl[wv][buf][row][0];

    // ---- em/ts pass (raw x): lane l16 covers t = c*64 + 4*l16 + {0..3} ----
    {
      const int t0 = 4 * l16;
      const int4 lb4 = *(const int4*)&ll[t0];
      int prev = (l16 == 0) ? lastl : ll[t0 - 1];
      const int gt0 = c * 64 + t0;
      const int lbls[4] = {lb4.x, lb4.y, lb4.z, lb4.w};
#pragma unroll
      for (int u = 0; u < 4; ++u) {
        const int gt  = gt0 + u;
        const int lbl = lbls[u];
        if (gt < mylen) {
          em += xreg[(t0 + u) * 16 + lbl];
          if (gt >= 1) ts += ldst[prev * 16 + lbl];
        }
        prev = lbl;
      }
      lastl = __shfl(lb4.w, (lane & 48) + 15, 64);
    }

    // ---- in-place x -> exp(x), lane-major stride (conflict-free) ----
#pragma unroll
    for (int q = 0; q < 4; ++q) {
      float4* p = (float4*)&ldsx[wv][buf][q * 1032];
#pragma unroll
      for (int f = 0; f < 4; ++f) {
        float4 v = p[f * 64 + lane];
        v.x = __builtin_amdgcn_exp2f(v.x * L2E);
        v.y = __builtin_amdgcn_exp2f(v.y * L2E);
        v.z = __builtin_amdgcn_exp2f(v.z * L2E);
        v.w = __builtin_amdgcn_exp2f(v.w * L2E);
        p[f * 64 + lane] = v;
      }
    }

    if (c == 0) av = xreg[l16];  // alpha_0 = exp(x[0][:]) (t=0 < mylen always)

    int tend = c * 64 + 63;
    if (tend > maxlen - 1) tend = maxlen - 1;
    const float* xp = &xreg[(t & 63) * 16 + l16];

    auto stepf = [&]() {
      const float xe = *xp;
      xp += 16;
      float a0 = av * m0;
      float a1 = dppf<0x124>(av) * m4;
      float a2 = dppf<0x128>(av) * m8;
      float a3 = dppf<0x12C>(av) * m12;
      a0 = __builtin_fmaf(dppf<0x121>(av), m1,  a0);
      a1 = __builtin_fmaf(dppf<0x125>(av), m5,  a1);
      a2 = __builtin_fmaf(dppf<0x129>(av), m9,  a2);
      a3 = __builtin_fmaf(dppf<0x12D>(av), m13, a3);
      a0 = __builtin_fmaf(dppf<0x122>(av), m2,  a0);
      a1 = __builtin_fmaf(dppf<0x126>(av), m6,  a1);
      a2 = __builtin_fmaf(dppf<0x12A>(av), m10, a2);
      a3 = __builtin_fmaf(dppf<0x12E>(av), m14, a3);
      a0 = __builtin_fmaf(dppf<0x123>(av), m3,  a0);
      a1 = __builtin_fmaf(dppf<0x127>(av), m7,  a1);
      a2 = __builtin_fmaf(dppf<0x12B>(av), m11, a2);
      a3 = __builtin_fmaf(dppf<0x12F>(av), m15, a3);
      const float acc = ((a0 + a1) + (a2 + a3)) * xe;
      av = (t < mylen) ? acc : av;  // freeze finished rows
      ++t;
    };

    while (t + 7 <= tend) {
#pragma unroll
      for (int u = 0; u < 8; ++u) stepf();
      renorm();
    }
    if (t <= tend) {
      while (t <= tend) stepf();
      renorm();
    }
  }

  // stot = per-row sum of alpha (direction-independent rotate-reduce)
  float stot = av;
  stot += dppf<0x128>(stot);
  stot += dppf<0x124>(stot);
  stot += dppf<0x122>(stot);
  stot += dppf<0x121>(stot);

  // reduce em/ts within the row
  em += __shfl_xor(em, 1, 64);
  em += __shfl_xor(em, 2, 64);
  em += __shfl_xor(em, 4, 64);
  em += __shfl_xor(em, 8, 64);
  ts += __shfl_xor(ts, 1, 64);
  ts += __shfl_xor(ts, 2, 64);
  ts += __shfl_xor(ts, 4, 64);
  ts += __shfl_xor(ts, 8, 64);

  const float z2  = (float)R2 + __builtin_amdgcn_logf(stot);  // log2
  const float res = z2 * LN2 - em - ts;
  if (l16 == 0) out[myb] = res;
}

extern "C" void kernel_launch(void* const* d_in, const int* in_sizes, int n_in,
                              void* d_out, int out_size, void* d_ws, size_t ws_size,
                              hipStream_t stream) {
  const float* x      = (const float*)d_in[0];
  const float* trans  = (const float*)d_in[1];
  const int*   label  = (const int*)d_in[2];
  const int*   length = (const int*)d_in[3];
  float* out = (float*)d_out;
  const int B = in_sizes[3];  // 4096
  crf_fwd<<<dim3(B / 16), dim3(256), 0, stream>>>(x, trans, label, length, out);
}